// Round 16
// baseline (267.676 us; speedup 1.0000x reference)
//
#include <hip/hip_runtime.h>
#include <hip/hip_fp16.h>
#include <math.h>

// ---------------------------------------------------------------------------
// GCN forward, fully fused, fp16 feature tables (fp32 accumulate).
//   xs  = fp16(dinv .* x)   [N,16] half (3.2 MB, L2-resident)
//   hs1 = fp16(dinv .* h1)  [N,32] half (6.4 MB)
// Edge layout: bucket b = 512 dst nodes, fixed-capacity gapped region of C
// edges at b*C. Lists sorted by (dstLocal, srcHalf): rowRange[n]=(beg,end),
// rowMid[n] = boundary between srcs < N/2 and srcs >= N/2.
// conv2 runs as two kernels so each one's random working set is one 3.2 MB
// contiguous half of hs1 (fits a 4 MiB per-XCD L2). All gather kernels use
// 8 lanes/node (grid 3125) for full occupancy.
// ---------------------------------------------------------------------------

#define BN 512           // nodes per bucket
#define BSH 9            // log2(BN)
#define NBUF 256         // max buckets (N <= 131072)
#define EPB 4096         // edges per scatter block
#define EPT 8            // edges per scatter thread (EPB/512)

__global__ void init_cursor(int* __restrict__ gCursor, int NB, int C) {
    int b = blockIdx.x * blockDim.x + threadIdx.x;
    if (b < NB) gCursor[b] = b * C;
}

// Scatter edges into bucket-gapped packed array ((src<<9)|dstLocal).
// 512 threads/block; single LDS-atomic pass, rank in registers.
__global__ void __launch_bounds__(512)
bucket_scatter(const int* __restrict__ row, const int* __restrict__ col,
               int* __restrict__ gCursor, int* __restrict__ packed,
               int E, int NB, int C) {
    __shared__ int hist[NBUF];
    __shared__ int base[NBUF];
    int t = threadIdx.x;
    int blockBase = blockIdx.x * EPB;
    for (int i = t; i < NB; i += 512) hist[i] = 0;
    __syncthreads();
    int pay[EPT];
    int meta[EPT];
#pragma unroll
    for (int k = 0; k < EPT; ++k) {
        int e = blockBase + k * 512 + t;
        if (e < E) {
            int c = col[e];
            int b = c >> BSH;
            int r = atomicAdd(&hist[b], 1);        // rank within (block,bucket)
            pay[k] = (row[e] << BSH) | (c & (BN - 1));
            meta[k] = (b << 16) | r;               // r < 4096 fits 16 bits
        } else {
            meta[k] = -1;
        }
    }
    __syncthreads();
    for (int b = t; b < NB; b += 512) {            // claim global ranges
        int c = hist[b];
        base[b] = c ? atomicAdd(&gCursor[b], c) : 0;
    }
    __syncthreads();
#pragma unroll
    for (int k = 0; k < EPT; ++k) {                // write
        int m = meta[k];
        if (m >= 0) {
            int b = m >> 16;
            int pos = base[b] + (m & 0xFFFF);
            if (pos < (b + 1) * C)                 // overflow guard (~16 sigma)
                packed[pos] = pay[k];
        }
    }
}

// Per bucket (1024 threads): 1024-bin hist (dstLocal*2 + srcHalf) -> rowRange
// + rowMid + dinv, counting-sort -> srcs[] ordered (dl, srcHalf), prescale xs.
// Scan via shfl wave-scan + cross-wave scan (2 barriers instead of 20).
__global__ void __launch_bounds__(1024)
bucket_finalize(const int* __restrict__ packed, const int* __restrict__ gCursor,
                int2* __restrict__ rowRange, int* __restrict__ rowMid,
                float* __restrict__ dinv, int* __restrict__ srcs,
                const float4* __restrict__ x4, __half* __restrict__ xs,
                int N, int C, int halfN) {
    __shared__ int cnt[BN * 2];
    __shared__ int cur[BN * 2];
    __shared__ float sdv[BN];
    __shared__ int wsum[16];
    int bkt = blockIdx.x;
    int t = threadIdx.x;
    int nodeBase = bkt << BSH;
    cnt[t] = 0;
    __syncthreads();
    int beg = bkt * C;
    int end = min(gCursor[bkt], beg + C);
    for (int e = beg + t; e < end; e += 1024) {
        int w = packed[e];
        int key = ((w & (BN - 1)) << 1) | ((w >> BSH) >= halfN ? 1 : 0);
        atomicAdd(&cnt[key], 1);
    }
    __syncthreads();
    // thread t (< BN) owns bins 2t,2t+1 = node t (local)
    int c0 = (t < BN) ? cnt[2 * t] : 0;
    int c1 = (t < BN) ? cnt[2 * t + 1] : 0;
    int s = c0 + c1;
    // inclusive scan of s: shfl within wave, then cross-wave offsets
    int lane = t & 63, wv = t >> 6;
    int v = s;
#pragma unroll
    for (int off = 1; off < 64; off <<= 1) {
        int u = __shfl_up(v, off);
        if (lane >= off) v += u;
    }
    if (lane == 63) wsum[wv] = v;
    __syncthreads();
    int addv = 0;
#pragma unroll
    for (int w = 0; w < 16; ++w) addv += (w < wv) ? wsum[w] : 0;
    v += addv;
    if (t < BN) {
        int p = beg + v - s;                       // exclusive prefix
        cur[2 * t] = p;
        cur[2 * t + 1] = p + c0;
        float d = rsqrtf((float)s + 1.0f);
        sdv[t] = d;
        int n = nodeBase + t;
        if (n < N) {
            rowRange[n] = make_int2(p, p + s);
            rowMid[n] = p + c0;
            dinv[n] = d;
        }
    }
    __syncthreads();
    for (int e = beg + t; e < end; e += 1024) {    // counting sort (2nd read: L2)
        int w = packed[e];
        int src = w >> BSH;
        int key = ((w & (BN - 1)) << 1) | (src >= halfN ? 1 : 0);
        int pos = atomicAdd(&cur[key], 1);
        srcs[pos] = src;
    }
    // prescale: xs = fp16(dinv .* x); 2 threads/node, 16B (8 halves) each
    {
        int n = t >> 1, hf = t & 1;                 // BN*2 == 1024 exactly
        int g = nodeBase + n;
        if (g < N) {
            float d = sdv[n];
            float4 va = x4[(size_t)g * 4 + hf * 2];
            float4 vb = x4[(size_t)g * 4 + hf * 2 + 1];
            __half2 h0 = __floats2half2_rn(va.x * d, va.y * d);
            __half2 h1 = __floats2half2_rn(va.z * d, va.w * d);
            __half2 h2 = __floats2half2_rn(vb.x * d, vb.y * d);
            __half2 h3 = __floats2half2_rn(vb.z * d, vb.w * d);
            uint4 u;
            u.x = *(unsigned*)&h0; u.y = *(unsigned*)&h1;
            u.z = *(unsigned*)&h2; u.w = *(unsigned*)&h3;
            *(uint4*)(xs + (size_t)g * 16 + hf * 8) = u;
        }
    }
}

__device__ __forceinline__ void acc4(float* a, uint2 u) {
    float2 f;
    f = __half22float2(*(const __half2*)&u.x); a[0] += f.x; a[1] += f.y;
    f = __half22float2(*(const __half2*)&u.y); a[2] += f.x; a[3] += f.y;
}

__device__ __forceinline__ void acc2(float* a, unsigned u) {
    float2 f = __half22float2(*(const __half2*)&u);
    a[0] += f.x; a[1] += f.y;
}

// Layer 1: gather xs (16ch half), fused W1 GEMM + bias + ReLU; hs1=fp16(dinv.*h1).
// 8 lanes per node, 4B (2 halves) each; block = 32 nodes, grid 3125.
__global__ void __launch_bounds__(256)
gather_conv1(const int2* __restrict__ rowRange, const int* __restrict__ srcs,
             const __half* __restrict__ xs, const float* __restrict__ dinv,
             const float* __restrict__ W1, const float* __restrict__ b1,
             __half* __restrict__ hs1, int N) {
    __shared__ float A[32][17];
    __shared__ float sW[512];
    __shared__ float sb[32];
    int t = threadIdx.x;
    for (int i = t; i < 512; i += 256) sW[i] = W1[i];
    if (t < 32) sb[t] = b1[t];
    int tt = blockIdx.x * 256 + t;
    int node = tt >> 3, q = tt & 7, ln = t >> 3;
    float a[2] = {0.f, 0.f};
    float di = 0.f;
    if (node < N) {
        int2 rr = rowRange[node];
        for (int e = rr.x; e < rr.y; ++e) {
            int s = srcs[e];
            acc2(a, *(const unsigned*)(xs + (size_t)s * 16 + q * 2));
        }
        acc2(a, *(const unsigned*)(xs + (size_t)node * 16 + q * 2));  // self
        di = dinv[node];
        a[0] *= di; a[1] *= di;
    }
    A[ln][q * 2 + 0] = a[0];
    A[ln][q * 2 + 1] = a[1];
    __syncthreads();
    if (node < N) {
        int k0 = q * 4;
        float acc[4];
#pragma unroll
        for (int j = 0; j < 4; ++j) acc[j] = sb[k0 + j];
#pragma unroll
        for (int c = 0; c < 16; ++c) {
            float ac = A[ln][c];
#pragma unroll
            for (int j = 0; j < 4; ++j) acc[j] += ac * sW[c * 32 + k0 + j];
        }
        __half2 h0 = __floats2half2_rn(di * fmaxf(acc[0], 0.f),
                                       di * fmaxf(acc[1], 0.f));
        __half2 h1 = __floats2half2_rn(di * fmaxf(acc[2], 0.f),
                                       di * fmaxf(acc[3], 0.f));
        uint2 u;
        u.x = *(unsigned*)&h0; u.y = *(unsigned*)&h1;
        *(uint2*)(hs1 + (size_t)node * 32 + k0) = u;
    }
}

// Conv2 phase A: sum lo-half srcs (hs1 rows [0,N/2) = contiguous 3.2 MB,
// per-XCD L2-resident) -> A2[N,32] fp32 coalesced. 8 lanes/node, grid 3125.
__global__ void __launch_bounds__(256)
gather_conv2_lo(const int2* __restrict__ rowRange, const int* __restrict__ rowMid,
                const int* __restrict__ srcs, const __half* __restrict__ hs1,
                float* __restrict__ A2, int N) {
    int tt = blockIdx.x * 256 + threadIdx.x;
    int node = tt >> 3, q = tt & 7;
    if (node >= N) return;
    float a[4] = {0.f, 0.f, 0.f, 0.f};
    int beg = rowRange[node].x, mid = rowMid[node];
    for (int e = beg; e < mid; ++e) {
        int s = srcs[e];
        acc4(a, *(const uint2*)(hs1 + (size_t)s * 32 + q * 4));
    }
    float4 r;
    r.x = a[0]; r.y = a[1]; r.z = a[2]; r.w = a[3];
    *(float4*)(A2 + (size_t)node * 32 + q * 4) = r;
}

// Conv2 phase B + head: hi-half srcs (hs1 rows [N/2,N) = 3.2 MB) + self +
// A2 partial; fused W2+b2+ReLU, Wl1+bl1+ReLU, Wl4+bl4. 8 lanes/node,
// 32 nodes/block, grid 3125.
__global__ void __launch_bounds__(256)
gather_conv2_hi_head(const int2* __restrict__ rowRange, const int* __restrict__ rowMid,
                     const int* __restrict__ srcs, const __half* __restrict__ hs1,
                     const float* __restrict__ A2, const float* __restrict__ dinv,
                     const float* __restrict__ W2, const float* __restrict__ b2,
                     const float* __restrict__ Wl1, const float* __restrict__ bl1,
                     const float* __restrict__ Wl4, const float* __restrict__ bl4,
                     float* __restrict__ out, int N) {
    __shared__ float A[32][33];
    __shared__ float sW2[1024];
    __shared__ float sWl1[1024];
    __shared__ float sb2[32], sbl1[32], sWl4[32];
    __shared__ float sbl4;
    int t = threadIdx.x;
    for (int i = t; i < 1024; i += 256) { sW2[i] = W2[i]; sWl1[i] = Wl1[i]; }
    if (t < 32) { sb2[t] = b2[t]; sbl1[t] = bl1[t]; sWl4[t] = Wl4[t]; }
    if (t == 0) sbl4 = bl4[0];
    int tt = blockIdx.x * 256 + t;
    int node = tt >> 3, q = tt & 7, ln = t >> 3;
    float a[4] = {0.f, 0.f, 0.f, 0.f};
    if (node < N) {
        int mid = rowMid[node], end = rowRange[node].y;
        for (int e = mid; e < end; ++e) {
            int s = srcs[e];
            acc4(a, *(const uint2*)(hs1 + (size_t)s * 32 + q * 4));
        }
        acc4(a, *(const uint2*)(hs1 + (size_t)node * 32 + q * 4));  // self
        // partial from phase A (coalesced)
        float4 l = *(const float4*)(A2 + (size_t)node * 32 + q * 4);
        a[0] += l.x; a[1] += l.y; a[2] += l.z; a[3] += l.w;
        float di = dinv[node];
#pragma unroll
        for (int j = 0; j < 4; ++j) a[j] *= di;
    }
#pragma unroll
    for (int j = 0; j < 4; ++j) A[ln][q * 4 + j] = a[j];
    __syncthreads();
    int k0 = q * 4;
    float h2[4];
#pragma unroll
    for (int j = 0; j < 4; ++j) h2[j] = sb2[k0 + j];
#pragma unroll
    for (int c = 0; c < 32; ++c) {
        float ac = A[ln][c];
#pragma unroll
        for (int j = 0; j < 4; ++j) h2[j] += ac * sW2[c * 32 + k0 + j];
    }
#pragma unroll
    for (int j = 0; j < 4; ++j) h2[j] = fmaxf(h2[j], 0.f);
    __syncthreads();
#pragma unroll
    for (int j = 0; j < 4; ++j) A[ln][k0 + j] = h2[j];
    __syncthreads();
    float h3[4];
#pragma unroll
    for (int j = 0; j < 4; ++j) h3[j] = sbl1[k0 + j];
#pragma unroll
    for (int c = 0; c < 32; ++c) {
        float ac = A[ln][c];
#pragma unroll
        for (int j = 0; j < 4; ++j) h3[j] += ac * sWl1[c * 32 + k0 + j];
    }
    float p = 0.f;
#pragma unroll
    for (int j = 0; j < 4; ++j) p += fmaxf(h3[j], 0.f) * sWl4[k0 + j];
    p += __shfl_xor(p, 1);
    p += __shfl_xor(p, 2);
    p += __shfl_xor(p, 4);
    if (q == 0 && node < N) out[node] = p + sbl4;
}

extern "C" void kernel_launch(void* const* d_in, const int* in_sizes, int n_in,
                              void* d_out, int out_size, void* d_ws, size_t ws_size,
                              hipStream_t stream) {
    const float* x   = (const float*)d_in[0];
    const int*   ei  = (const int*)d_in[1];
    const float* W1  = (const float*)d_in[2];
    const float* b1  = (const float*)d_in[3];
    const float* W2  = (const float*)d_in[4];
    const float* b2  = (const float*)d_in[5];
    const float* Wl1 = (const float*)d_in[6];
    const float* bl1 = (const float*)d_in[7];
    const float* Wl4 = (const float*)d_in[8];
    const float* bl4 = (const float*)d_in[9];
    float* out = (float*)d_out;

    const int N = in_sizes[0] / 16;
    const int E = in_sizes[1] / 2;
    const int* row = ei;        // edge_index[0] : source j
    const int* col = ei + E;    // edge_index[1] : target i
    const int NB = (N + BN - 1) >> BSH;
    const int halfN = N / 2;
    // fixed per-bucket capacity: mean * 1.125, rounded up to 64
    int C = (E + NB - 1) / NB;
    C = (C * 9 + 7) / 8;
    C = (C + 63) & ~63;

    // workspace layout (512B aligned)
    char* ws = (char*)d_ws;
    auto align = [](size_t v) { return (v + 511) & ~(size_t)511; };
    size_t o = 0;
    int*    gCursor  = (int*)(ws + o);    o = align(o + (size_t)NBUF * 4);
    int2*   rowRange = (int2*)(ws + o);   o = align(o + (size_t)N * 8);
    int*    rowMid   = (int*)(ws + o);    o = align(o + (size_t)N * 4);
    float*  dinv     = (float*)(ws + o);  o = align(o + (size_t)N * 4);
    int*    packed   = (int*)(ws + o);    o = align(o + (size_t)NB * C * 4);
    int*    srcs     = (int*)(ws + o);    o = align(o + (size_t)NB * C * 4);
    __half* xs       = (__half*)(ws + o); o = align(o + (size_t)N * 16 * 2);
    __half* hs1      = (__half*)(ws + o); o = align(o + (size_t)N * 32 * 2);
    float*  A2       = (float*)(ws + o);  o = align(o + (size_t)N * 32 * 4);

    const int BLK = 256;
    int gridSc = (E + EPB - 1) / EPB;
    int gridG8 = (N * 8 + BLK - 1) / BLK;

    // --- edge reorder + degrees + prescale ---
    init_cursor<<<1, BLK, 0, stream>>>(gCursor, NB, C);
    bucket_scatter<<<gridSc, 512, 0, stream>>>(row, col, gCursor, packed, E, NB, C);
    bucket_finalize<<<NB, 1024, 0, stream>>>(packed, gCursor, rowRange, rowMid, dinv,
                                             srcs, (const float4*)x, xs, N, C, halfN);

    // --- conv1 (gather xs + fused W1) ---
    gather_conv1<<<gridG8, BLK, 0, stream>>>(rowRange, srcs, xs, dinv, W1, b1, hs1, N);

    // --- conv2 two-phase (each phase's random set = one 3.2 MB half of hs1) ---
    gather_conv2_lo<<<gridG8, BLK, 0, stream>>>(rowRange, rowMid, srcs, hs1, A2, N);
    gather_conv2_hi_head<<<gridG8, BLK, 0, stream>>>(rowRange, rowMid, srcs, hs1, A2,
                                                     dinv, W2, b2, Wl1, bl1,
                                                     Wl4, bl4, out, N);
}

// Round 17
// 227.074 us; speedup vs baseline: 1.1788x; 1.1788x over previous
//
#include <hip/hip_runtime.h>
#include <hip/hip_fp16.h>
#include <math.h>

// ---------------------------------------------------------------------------
// GCN forward, fully fused, fp16 feature tables (fp32 accumulate).
//   xs  = fp16(dinv .* x)   [N,16] half (3.2 MB, L2-resident)
//   hs1 = fp16(dinv .* h1)  [N,32] half (6.4 MB)
// Edge layout: bucket b = 512 dst nodes, fixed-capacity gapped region of C
// edges at b*C. Lists sorted by (dstLocal, srcHalf): rowRange[n]=(beg,end),
// rowMid[n] = boundary between srcs < N/2 and srcs >= N/2.
// conv2 runs as two kernels so each one's random working set is one 3.2 MB
// contiguous half of hs1 (fits a 4 MiB per-XCD L2).
// Gathers: 8 lanes/node = (edge-offset x row-part) so per-lane loads stay
// 16 B while the grid is 3125 blocks (full occupancy cap).
// ---------------------------------------------------------------------------

#define BN 512           // nodes per bucket
#define BSH 9            // log2(BN)
#define NBUF 256         // max buckets (N <= 131072)
#define EPB 4096         // edges per scatter block
#define EPT 8            // edges per scatter thread (EPB/512)

__global__ void init_cursor(int* __restrict__ gCursor, int NB, int C) {
    int b = blockIdx.x * blockDim.x + threadIdx.x;
    if (b < NB) gCursor[b] = b * C;
}

// Scatter edges into bucket-gapped packed array ((src<<9)|dstLocal).
// 512 threads/block; single LDS-atomic pass, rank in registers.
__global__ void __launch_bounds__(512)
bucket_scatter(const int* __restrict__ row, const int* __restrict__ col,
               int* __restrict__ gCursor, int* __restrict__ packed,
               int E, int NB, int C) {
    __shared__ int hist[NBUF];
    __shared__ int base[NBUF];
    int t = threadIdx.x;
    int blockBase = blockIdx.x * EPB;
    for (int i = t; i < NB; i += 512) hist[i] = 0;
    __syncthreads();
    int pay[EPT];
    int meta[EPT];
#pragma unroll
    for (int k = 0; k < EPT; ++k) {
        int e = blockBase + k * 512 + t;
        if (e < E) {
            int c = col[e];
            int b = c >> BSH;
            int r = atomicAdd(&hist[b], 1);        // rank within (block,bucket)
            pay[k] = (row[e] << BSH) | (c & (BN - 1));
            meta[k] = (b << 16) | r;               // r < 4096 fits 16 bits
        } else {
            meta[k] = -1;
        }
    }
    __syncthreads();
    for (int b = t; b < NB; b += 512) {            // claim global ranges
        int c = hist[b];
        base[b] = c ? atomicAdd(&gCursor[b], c) : 0;
    }
    __syncthreads();
#pragma unroll
    for (int k = 0; k < EPT; ++k) {                // write
        int m = meta[k];
        if (m >= 0) {
            int b = m >> 16;
            int pos = base[b] + (m & 0xFFFF);
            if (pos < (b + 1) * C)                 // overflow guard (~16 sigma)
                packed[pos] = pay[k];
        }
    }
}

// Per bucket (1024 threads): 1024-bin hist (dstLocal*2 + srcHalf) -> rowRange
// + rowMid + dinv, counting-sort -> srcs[] ordered (dl, srcHalf), prescale xs.
// Scan via shfl wave-scan + cross-wave scan.
__global__ void __launch_bounds__(1024)
bucket_finalize(const int* __restrict__ packed, const int* __restrict__ gCursor,
                int2* __restrict__ rowRange, int* __restrict__ rowMid,
                float* __restrict__ dinv, int* __restrict__ srcs,
                const float4* __restrict__ x4, __half* __restrict__ xs,
                int N, int C, int halfN) {
    __shared__ int cnt[BN * 2];
    __shared__ int cur[BN * 2];
    __shared__ float sdv[BN];
    __shared__ int wsum[16];
    int bkt = blockIdx.x;
    int t = threadIdx.x;
    int nodeBase = bkt << BSH;
    cnt[t] = 0;
    __syncthreads();
    int beg = bkt * C;
    int end = min(gCursor[bkt], beg + C);
    for (int e = beg + t; e < end; e += 1024) {
        int w = packed[e];
        int key = ((w & (BN - 1)) << 1) | ((w >> BSH) >= halfN ? 1 : 0);
        atomicAdd(&cnt[key], 1);
    }
    __syncthreads();
    // thread t (< BN) owns bins 2t,2t+1 = node t (local)
    int c0 = (t < BN) ? cnt[2 * t] : 0;
    int c1 = (t < BN) ? cnt[2 * t + 1] : 0;
    int s = c0 + c1;
    // inclusive scan of s: shfl within wave, then cross-wave offsets
    int lane = t & 63, wv = t >> 6;
    int v = s;
#pragma unroll
    for (int off = 1; off < 64; off <<= 1) {
        int u = __shfl_up(v, off);
        if (lane >= off) v += u;
    }
    if (lane == 63) wsum[wv] = v;
    __syncthreads();
    int addv = 0;
#pragma unroll
    for (int w = 0; w < 16; ++w) addv += (w < wv) ? wsum[w] : 0;
    v += addv;
    if (t < BN) {
        int p = beg + v - s;                       // exclusive prefix
        cur[2 * t] = p;
        cur[2 * t + 1] = p + c0;
        float d = rsqrtf((float)s + 1.0f);
        sdv[t] = d;
        int n = nodeBase + t;
        if (n < N) {
            rowRange[n] = make_int2(p, p + s);
            rowMid[n] = p + c0;
            dinv[n] = d;
        }
    }
    __syncthreads();
    for (int e = beg + t; e < end; e += 1024) {    // counting sort (2nd read: L2)
        int w = packed[e];
        int src = w >> BSH;
        int key = ((w & (BN - 1)) << 1) | (src >= halfN ? 1 : 0);
        int pos = atomicAdd(&cur[key], 1);
        srcs[pos] = src;
    }
    // prescale: xs = fp16(dinv .* x); 2 threads/node, 16B (8 halves) each
    {
        int n = t >> 1, hf = t & 1;                 // BN*2 == 1024 exactly
        int g = nodeBase + n;
        if (g < N) {
            float d = sdv[n];
            float4 va = x4[(size_t)g * 4 + hf * 2];
            float4 vb = x4[(size_t)g * 4 + hf * 2 + 1];
            __half2 h0 = __floats2half2_rn(va.x * d, va.y * d);
            __half2 h1 = __floats2half2_rn(va.z * d, va.w * d);
            __half2 h2 = __floats2half2_rn(vb.x * d, vb.y * d);
            __half2 h3 = __floats2half2_rn(vb.z * d, vb.w * d);
            uint4 u;
            u.x = *(unsigned*)&h0; u.y = *(unsigned*)&h1;
            u.z = *(unsigned*)&h2; u.w = *(unsigned*)&h3;
            *(uint4*)(xs + (size_t)g * 16 + hf * 8) = u;
        }
    }
}

__device__ __forceinline__ void acc8(float* a, uint4 u) {
    float2 f;
    f = __half22float2(*(const __half2*)&u.x); a[0] += f.x; a[1] += f.y;
    f = __half22float2(*(const __half2*)&u.y); a[2] += f.x; a[3] += f.y;
    f = __half22float2(*(const __half2*)&u.z); a[4] += f.x; a[5] += f.y;
    f = __half22float2(*(const __half2*)&u.w); a[6] += f.x; a[7] += f.y;
}

// Layer 1: gather xs (16ch half), fused W1 GEMM + bias + ReLU; hs1=fp16(dinv.*h1).
// 8 lanes/node = (eo in [0,4)) x (hf in [0,2)): lane handles edges beg+eo
// step 4, loading the 16B half-row hf. Reduce over eo via shfl. Grid 3125.
__global__ void __launch_bounds__(256)
gather_conv1(const int2* __restrict__ rowRange, const int* __restrict__ srcs,
             const __half* __restrict__ xs, const float* __restrict__ dinv,
             const float* __restrict__ W1, const float* __restrict__ b1,
             __half* __restrict__ hs1, int N) {
    __shared__ float A[32][17];
    __shared__ float sW[512];
    __shared__ float sb[32];
    int t = threadIdx.x;
    for (int i = t; i < 512; i += 256) sW[i] = W1[i];
    if (t < 32) sb[t] = b1[t];
    int tt = blockIdx.x * 256 + t;
    int node = tt >> 3, q = tt & 7, ln = t >> 3;
    int eo = q >> 1, hf = q & 1;
    float a[8] = {0.f, 0.f, 0.f, 0.f, 0.f, 0.f, 0.f, 0.f};
    float di = 0.f;
    if (node < N) {
        int2 rr = rowRange[node];
        for (int e = rr.x + eo; e < rr.y; e += 4) {
            int s = srcs[e];
            acc8(a, *(const uint4*)(xs + (size_t)s * 16 + hf * 8));
        }
        if (eo == 0)                                // self, counted once
            acc8(a, *(const uint4*)(xs + (size_t)node * 16 + hf * 8));
        di = dinv[node];
    }
    // reduce over eo (q bits 1..2)
#pragma unroll
    for (int j = 0; j < 8; ++j) {
        a[j] += __shfl_xor(a[j], 2);
        a[j] += __shfl_xor(a[j], 4);
        a[j] *= di;
    }
    if (eo == 0) {                                  // q = 0 (hf0), 1 (hf1)
#pragma unroll
        for (int j = 0; j < 8; ++j) A[ln][hf * 8 + j] = a[j];
    }
    __syncthreads();
    if (node < N) {
        int k0 = q * 4;
        float acc[4];
#pragma unroll
        for (int j = 0; j < 4; ++j) acc[j] = sb[k0 + j];
#pragma unroll
        for (int c = 0; c < 16; ++c) {
            float ac = A[ln][c];
#pragma unroll
            for (int j = 0; j < 4; ++j) acc[j] += ac * sW[c * 32 + k0 + j];
        }
        __half2 h0 = __floats2half2_rn(di * fmaxf(acc[0], 0.f),
                                       di * fmaxf(acc[1], 0.f));
        __half2 h1 = __floats2half2_rn(di * fmaxf(acc[2], 0.f),
                                       di * fmaxf(acc[3], 0.f));
        uint2 u;
        u.x = *(unsigned*)&h0; u.y = *(unsigned*)&h1;
        *(uint2*)(hs1 + (size_t)node * 32 + k0) = u;
    }
}

// Conv2 phase A: sum lo-half srcs (hs1 rows [0,N/2) = 3.2 MB, L2-resident)
// -> A2[N,32] fp32. 8 lanes/node = (eo in [0,2)) x (part in [0,4)): lane
// handles edges beg+eo step 2, 16B part of the 64B row. Grid 3125.
__global__ void __launch_bounds__(256)
gather_conv2_lo(const int2* __restrict__ rowRange, const int* __restrict__ rowMid,
                const int* __restrict__ srcs, const __half* __restrict__ hs1,
                float* __restrict__ A2, int N) {
    int tt = blockIdx.x * 256 + threadIdx.x;
    int node = tt >> 3, q = tt & 7;
    int eo = q >> 2, part = q & 3;
    float a[8] = {0.f, 0.f, 0.f, 0.f, 0.f, 0.f, 0.f, 0.f};
    if (node < N) {
        int beg = rowRange[node].x, mid = rowMid[node];
        for (int e = beg + eo; e < mid; e += 2) {
            int s = srcs[e];
            acc8(a, *(const uint4*)(hs1 + (size_t)s * 32 + part * 8));
        }
    }
#pragma unroll
    for (int j = 0; j < 8; ++j) a[j] += __shfl_xor(a[j], 4);
    if (node < N && eo == 0) {
        float4 r0, r1;
        r0.x = a[0]; r0.y = a[1]; r0.z = a[2]; r0.w = a[3];
        r1.x = a[4]; r1.y = a[5]; r1.z = a[6]; r1.w = a[7];
        *(float4*)(A2 + (size_t)node * 32 + part * 8) = r0;
        *(float4*)(A2 + (size_t)node * 32 + part * 8 + 4) = r1;
    }
}

// Conv2 phase B + head: hi-half srcs (hs1 rows [N/2,N) = 3.2 MB) + self +
// A2 partial; fused W2+b2+ReLU, Wl1+bl1+ReLU, Wl4+bl4. Same 8-lane split.
__global__ void __launch_bounds__(256)
gather_conv2_hi_head(const int2* __restrict__ rowRange, const int* __restrict__ rowMid,
                     const int* __restrict__ srcs, const __half* __restrict__ hs1,
                     const float* __restrict__ A2, const float* __restrict__ dinv,
                     const float* __restrict__ W2, const float* __restrict__ b2,
                     const float* __restrict__ Wl1, const float* __restrict__ bl1,
                     const float* __restrict__ Wl4, const float* __restrict__ bl4,
                     float* __restrict__ out, int N) {
    __shared__ float A[32][33];
    __shared__ float sW2[1024];
    __shared__ float sWl1[1024];
    __shared__ float sb2[32], sbl1[32], sWl4[32];
    __shared__ float sbl4;
    int t = threadIdx.x;
    for (int i = t; i < 1024; i += 256) { sW2[i] = W2[i]; sWl1[i] = Wl1[i]; }
    if (t < 32) { sb2[t] = b2[t]; sbl1[t] = bl1[t]; sWl4[t] = Wl4[t]; }
    if (t == 0) sbl4 = bl4[0];
    int tt = blockIdx.x * 256 + t;
    int node = tt >> 3, q = tt & 7, ln = t >> 3;
    int eo = q >> 2, part = q & 3;
    float a[8] = {0.f, 0.f, 0.f, 0.f, 0.f, 0.f, 0.f, 0.f};
    if (node < N) {
        int mid = rowMid[node], end = rowRange[node].y;
        for (int e = mid + eo; e < end; e += 2) {
            int s = srcs[e];
            acc8(a, *(const uint4*)(hs1 + (size_t)s * 32 + part * 8));
        }
        if (eo == 0)                                // self, counted once
            acc8(a, *(const uint4*)(hs1 + (size_t)node * 32 + part * 8));
    }
#pragma unroll
    for (int j = 0; j < 8; ++j) a[j] += __shfl_xor(a[j], 4);
    if (node < N && eo == 0) {
        float4 l0 = *(const float4*)(A2 + (size_t)node * 32 + part * 8);
        float4 l1 = *(const float4*)(A2 + (size_t)node * 32 + part * 8 + 4);
        a[0] += l0.x; a[1] += l0.y; a[2] += l0.z; a[3] += l0.w;
        a[4] += l1.x; a[5] += l1.y; a[6] += l1.z; a[7] += l1.w;
        float di = dinv[node];
#pragma unroll
        for (int j = 0; j < 8; ++j) a[j] *= di;
#pragma unroll
        for (int j = 0; j < 8; ++j) A[ln][part * 8 + j] = a[j];
    }
    __syncthreads();
    int k0 = q * 4;
    float h2[4];
#pragma unroll
    for (int j = 0; j < 4; ++j) h2[j] = sb2[k0 + j];
#pragma unroll
    for (int c = 0; c < 32; ++c) {
        float ac = A[ln][c];
#pragma unroll
        for (int j = 0; j < 4; ++j) h2[j] += ac * sW2[c * 32 + k0 + j];
    }
#pragma unroll
    for (int j = 0; j < 4; ++j) h2[j] = fmaxf(h2[j], 0.f);
    __syncthreads();
#pragma unroll
    for (int j = 0; j < 4; ++j) A[ln][k0 + j] = h2[j];
    __syncthreads();
    float h3[4];
#pragma unroll
    for (int j = 0; j < 4; ++j) h3[j] = sbl1[k0 + j];
#pragma unroll
    for (int c = 0; c < 32; ++c) {
        float ac = A[ln][c];
#pragma unroll
        for (int j = 0; j < 4; ++j) h3[j] += ac * sWl1[c * 32 + k0 + j];
    }
    float p = 0.f;
#pragma unroll
    for (int j = 0; j < 4; ++j) p += fmaxf(h3[j], 0.f) * sWl4[k0 + j];
    p += __shfl_xor(p, 1);
    p += __shfl_xor(p, 2);
    p += __shfl_xor(p, 4);
    if (q == 0 && node < N) out[node] = p + sbl4;
}

extern "C" void kernel_launch(void* const* d_in, const int* in_sizes, int n_in,
                              void* d_out, int out_size, void* d_ws, size_t ws_size,
                              hipStream_t stream) {
    const float* x   = (const float*)d_in[0];
    const int*   ei  = (const int*)d_in[1];
    const float* W1  = (const float*)d_in[2];
    const float* b1  = (const float*)d_in[3];
    const float* W2  = (const float*)d_in[4];
    const float* b2  = (const float*)d_in[5];
    const float* Wl1 = (const float*)d_in[6];
    const float* bl1 = (const float*)d_in[7];
    const float* Wl4 = (const float*)d_in[8];
    const float* bl4 = (const float*)d_in[9];
    float* out = (float*)d_out;

    const int N = in_sizes[0] / 16;
    const int E = in_sizes[1] / 2;
    const int* row = ei;        // edge_index[0] : source j
    const int* col = ei + E;    // edge_index[1] : target i
    const int NB = (N + BN - 1) >> BSH;
    const int halfN = N / 2;
    // fixed per-bucket capacity: mean * 1.125, rounded up to 64
    int C = (E + NB - 1) / NB;
    C = (C * 9 + 7) / 8;
    C = (C + 63) & ~63;

    // workspace layout (512B aligned)
    char* ws = (char*)d_ws;
    auto align = [](size_t v) { return (v + 511) & ~(size_t)511; };
    size_t o = 0;
    int*    gCursor  = (int*)(ws + o);    o = align(o + (size_t)NBUF * 4);
    int2*   rowRange = (int2*)(ws + o);   o = align(o + (size_t)N * 8);
    int*    rowMid   = (int*)(ws + o);    o = align(o + (size_t)N * 4);
    float*  dinv     = (float*)(ws + o);  o = align(o + (size_t)N * 4);
    int*    packed   = (int*)(ws + o);    o = align(o + (size_t)NB * C * 4);
    int*    srcs     = (int*)(ws + o);    o = align(o + (size_t)NB * C * 4);
    __half* xs       = (__half*)(ws + o); o = align(o + (size_t)N * 16 * 2);
    __half* hs1      = (__half*)(ws + o); o = align(o + (size_t)N * 32 * 2);
    float*  A2       = (float*)(ws + o);  o = align(o + (size_t)N * 32 * 4);

    const int BLK = 256;
    int gridSc = (E + EPB - 1) / EPB;
    int gridG8 = (N * 8 + BLK - 1) / BLK;

    // --- edge reorder + degrees + prescale ---
    init_cursor<<<1, BLK, 0, stream>>>(gCursor, NB, C);
    bucket_scatter<<<gridSc, 512, 0, stream>>>(row, col, gCursor, packed, E, NB, C);
    bucket_finalize<<<NB, 1024, 0, stream>>>(packed, gCursor, rowRange, rowMid, dinv,
                                             srcs, (const float4*)x, xs, N, C, halfN);

    // --- conv1 (gather xs + fused W1) ---
    gather_conv1<<<gridG8, BLK, 0, stream>>>(rowRange, srcs, xs, dinv, W1, b1, hs1, N);

    // --- conv2 two-phase (each phase's random set = one 3.2 MB half of hs1) ---
    gather_conv2_lo<<<gridG8, BLK, 0, stream>>>(rowRange, rowMid, srcs, hs1, A2, N);
    gather_conv2_hi_head<<<gridG8, BLK, 0, stream>>>(rowRange, rowMid, srcs, hs1, A2,
                                                     dinv, W2, b2, Wl1, bl1,
                                                     Wl4, bl4, out, N);
}

// Round 18
// 216.907 us; speedup vs baseline: 1.2341x; 1.0469x over previous
//
#include <hip/hip_runtime.h>
#include <hip/hip_fp16.h>
#include <math.h>

// ---------------------------------------------------------------------------
// GCN forward, fully fused, fp16 feature tables (fp32 accumulate).
//   xs  = fp16(dinv .* x)   [N,16] half (3.2 MB, L2-resident)
//   hs1 = fp16(dinv .* h1)  [N,32] half (6.4 MB)
// Edge layout: bucket b = 512 dst nodes, fixed-capacity gapped region of C
// edges at b*C. Lists sorted by (dstLocal, srcHalf): rowRange[n]=(beg,end),
// rowMid[n] = boundary between srcs < N/2 and srcs >= N/2.
// conv2 runs as two kernels so each one's random working set is one 3.2 MB
// contiguous half of hs1 (fits a 4 MiB per-XCD L2).
// Gathers: 8 lanes/node = (edge-offset x row-part), 16 B loads, grid 3125;
// srcs index loads are software-pipelined one iteration ahead.
// ---------------------------------------------------------------------------

#define BN 512           // nodes per bucket
#define BSH 9            // log2(BN)
#define NBUF 256         // max buckets (N <= 131072)
#define EPB 4096         // edges per scatter block
#define EPT 8            // edges per scatter thread (EPB/512)

__global__ void init_cursor(int* __restrict__ gCursor, int NB, int C) {
    int b = blockIdx.x * blockDim.x + threadIdx.x;
    if (b < NB) gCursor[b] = b * C;
}

// Scatter edges into bucket-gapped packed array ((src<<9)|dstLocal).
// 512 threads/block; single LDS-atomic pass, rank in registers.
__global__ void __launch_bounds__(512)
bucket_scatter(const int* __restrict__ row, const int* __restrict__ col,
               int* __restrict__ gCursor, int* __restrict__ packed,
               int E, int NB, int C) {
    __shared__ int hist[NBUF];
    __shared__ int base[NBUF];
    int t = threadIdx.x;
    int blockBase = blockIdx.x * EPB;
    for (int i = t; i < NB; i += 512) hist[i] = 0;
    __syncthreads();
    int pay[EPT];
    int meta[EPT];
#pragma unroll
    for (int k = 0; k < EPT; ++k) {
        int e = blockBase + k * 512 + t;
        if (e < E) {
            int c = col[e];
            int b = c >> BSH;
            int r = atomicAdd(&hist[b], 1);        // rank within (block,bucket)
            pay[k] = (row[e] << BSH) | (c & (BN - 1));
            meta[k] = (b << 16) | r;               // r < 4096 fits 16 bits
        } else {
            meta[k] = -1;
        }
    }
    __syncthreads();
    for (int b = t; b < NB; b += 512) {            // claim global ranges
        int c = hist[b];
        base[b] = c ? atomicAdd(&gCursor[b], c) : 0;
    }
    __syncthreads();
#pragma unroll
    for (int k = 0; k < EPT; ++k) {                // write
        int m = meta[k];
        if (m >= 0) {
            int b = m >> 16;
            int pos = base[b] + (m & 0xFFFF);
            if (pos < (b + 1) * C)                 // overflow guard (~16 sigma)
                packed[pos] = pay[k];
        }
    }
}

// Per bucket (1024 threads): 1024-bin hist (dstLocal*2 + srcHalf) -> rowRange
// + rowMid + dinv, counting-sort -> srcs[] ordered (dl, srcHalf), prescale xs.
// Scan via shfl wave-scan + cross-wave scan.
__global__ void __launch_bounds__(1024)
bucket_finalize(const int* __restrict__ packed, const int* __restrict__ gCursor,
                int2* __restrict__ rowRange, int* __restrict__ rowMid,
                float* __restrict__ dinv, int* __restrict__ srcs,
                const float4* __restrict__ x4, __half* __restrict__ xs,
                int N, int C, int halfN) {
    __shared__ int cnt[BN * 2];
    __shared__ int cur[BN * 2];
    __shared__ float sdv[BN];
    __shared__ int wsum[16];
    int bkt = blockIdx.x;
    int t = threadIdx.x;
    int nodeBase = bkt << BSH;
    cnt[t] = 0;
    __syncthreads();
    int beg = bkt * C;
    int end = min(gCursor[bkt], beg + C);
    for (int e = beg + t; e < end; e += 1024) {
        int w = packed[e];
        int key = ((w & (BN - 1)) << 1) | ((w >> BSH) >= halfN ? 1 : 0);
        atomicAdd(&cnt[key], 1);
    }
    __syncthreads();
    // thread t (< BN) owns bins 2t,2t+1 = node t (local)
    int c0 = (t < BN) ? cnt[2 * t] : 0;
    int c1 = (t < BN) ? cnt[2 * t + 1] : 0;
    int s = c0 + c1;
    // inclusive scan of s: shfl within wave, then cross-wave offsets
    int lane = t & 63, wv = t >> 6;
    int v = s;
#pragma unroll
    for (int off = 1; off < 64; off <<= 1) {
        int u = __shfl_up(v, off);
        if (lane >= off) v += u;
    }
    if (lane == 63) wsum[wv] = v;
    __syncthreads();
    int addv = 0;
#pragma unroll
    for (int w = 0; w < 16; ++w) addv += (w < wv) ? wsum[w] : 0;
    v += addv;
    if (t < BN) {
        int p = beg + v - s;                       // exclusive prefix
        cur[2 * t] = p;
        cur[2 * t + 1] = p + c0;
        float d = rsqrtf((float)s + 1.0f);
        sdv[t] = d;
        int n = nodeBase + t;
        if (n < N) {
            rowRange[n] = make_int2(p, p + s);
            rowMid[n] = p + c0;
            dinv[n] = d;
        }
    }
    __syncthreads();
    for (int e = beg + t; e < end; e += 1024) {    // counting sort (2nd read: L2)
        int w = packed[e];
        int src = w >> BSH;
        int key = ((w & (BN - 1)) << 1) | (src >= halfN ? 1 : 0);
        int pos = atomicAdd(&cur[key], 1);
        srcs[pos] = src;
    }
    // prescale: xs = fp16(dinv .* x); 2 threads/node, 16B (8 halves) each
    {
        int n = t >> 1, hf = t & 1;                 // BN*2 == 1024 exactly
        int g = nodeBase + n;
        if (g < N) {
            float d = sdv[n];
            float4 va = x4[(size_t)g * 4 + hf * 2];
            float4 vb = x4[(size_t)g * 4 + hf * 2 + 1];
            __half2 h0 = __floats2half2_rn(va.x * d, va.y * d);
            __half2 h1 = __floats2half2_rn(va.z * d, va.w * d);
            __half2 h2 = __floats2half2_rn(vb.x * d, vb.y * d);
            __half2 h3 = __floats2half2_rn(vb.z * d, vb.w * d);
            uint4 u;
            u.x = *(unsigned*)&h0; u.y = *(unsigned*)&h1;
            u.z = *(unsigned*)&h2; u.w = *(unsigned*)&h3;
            *(uint4*)(xs + (size_t)g * 16 + hf * 8) = u;
        }
    }
}

__device__ __forceinline__ void acc8(float* a, uint4 u) {
    float2 f;
    f = __half22float2(*(const __half2*)&u.x); a[0] += f.x; a[1] += f.y;
    f = __half22float2(*(const __half2*)&u.y); a[2] += f.x; a[3] += f.y;
    f = __half22float2(*(const __half2*)&u.z); a[4] += f.x; a[5] += f.y;
    f = __half22float2(*(const __half2*)&u.w); a[6] += f.x; a[7] += f.y;
}

// Layer 1: gather xs (16ch half), fused W1 GEMM + bias + ReLU; hs1=fp16(dinv.*h1).
// 8 lanes/node = (eo in [0,4)) x (hf in [0,2)); srcs pipelined 1 iter ahead.
__global__ void __launch_bounds__(256)
gather_conv1(const int2* __restrict__ rowRange, const int* __restrict__ srcs,
             const __half* __restrict__ xs, const float* __restrict__ dinv,
             const float* __restrict__ W1, const float* __restrict__ b1,
             __half* __restrict__ hs1, int N) {
    __shared__ float A[32][17];
    __shared__ float sW[512];
    __shared__ float sb[32];
    int t = threadIdx.x;
    for (int i = t; i < 512; i += 256) sW[i] = W1[i];
    if (t < 32) sb[t] = b1[t];
    int tt = blockIdx.x * 256 + t;
    int node = tt >> 3, q = tt & 7, ln = t >> 3;
    int eo = q >> 1, hf = q & 1;
    float a[8] = {0.f, 0.f, 0.f, 0.f, 0.f, 0.f, 0.f, 0.f};
    float di = 0.f;
    if (node < N) {
        int2 rr = rowRange[node];
        int e = rr.x + eo;
        if (e < rr.y) {
            int s = srcs[e];
            for (; e + 4 < rr.y; e += 4) {
                int snext = srcs[e + 4];            // pipelined ahead
                acc8(a, *(const uint4*)(xs + (size_t)s * 16 + hf * 8));
                s = snext;
            }
            acc8(a, *(const uint4*)(xs + (size_t)s * 16 + hf * 8));
        }
        if (eo == 0)                                // self, counted once
            acc8(a, *(const uint4*)(xs + (size_t)node * 16 + hf * 8));
        di = dinv[node];
    }
    // reduce over eo (q bits 1..2)
#pragma unroll
    for (int j = 0; j < 8; ++j) {
        a[j] += __shfl_xor(a[j], 2);
        a[j] += __shfl_xor(a[j], 4);
        a[j] *= di;
    }
    if (eo == 0) {                                  // q = 0 (hf0), 1 (hf1)
#pragma unroll
        for (int j = 0; j < 8; ++j) A[ln][hf * 8 + j] = a[j];
    }
    __syncthreads();
    if (node < N) {
        int k0 = q * 4;
        float acc[4];
#pragma unroll
        for (int j = 0; j < 4; ++j) acc[j] = sb[k0 + j];
#pragma unroll
        for (int c = 0; c < 16; ++c) {
            float ac = A[ln][c];
#pragma unroll
            for (int j = 0; j < 4; ++j) acc[j] += ac * sW[c * 32 + k0 + j];
        }
        __half2 h0 = __floats2half2_rn(di * fmaxf(acc[0], 0.f),
                                       di * fmaxf(acc[1], 0.f));
        __half2 h1 = __floats2half2_rn(di * fmaxf(acc[2], 0.f),
                                       di * fmaxf(acc[3], 0.f));
        uint2 u;
        u.x = *(unsigned*)&h0; u.y = *(unsigned*)&h1;
        *(uint2*)(hs1 + (size_t)node * 32 + k0) = u;
    }
}

// Conv2 phase A: sum lo-half srcs (hs1 rows [0,N/2) = 3.2 MB, L2-resident)
// -> A2[N,32] fp32. 8 lanes/node = (eo in [0,2)) x (part in [0,4)).
__global__ void __launch_bounds__(256)
gather_conv2_lo(const int2* __restrict__ rowRange, const int* __restrict__ rowMid,
                const int* __restrict__ srcs, const __half* __restrict__ hs1,
                float* __restrict__ A2, int N) {
    int tt = blockIdx.x * 256 + threadIdx.x;
    int node = tt >> 3, q = tt & 7;
    int eo = q >> 2, part = q & 3;
    float a[8] = {0.f, 0.f, 0.f, 0.f, 0.f, 0.f, 0.f, 0.f};
    if (node < N) {
        int beg = rowRange[node].x, mid = rowMid[node];
        int e = beg + eo;
        if (e < mid) {
            int s = srcs[e];
            for (; e + 2 < mid; e += 2) {
                int snext = srcs[e + 2];            // pipelined ahead
                acc8(a, *(const uint4*)(hs1 + (size_t)s * 32 + part * 8));
                s = snext;
            }
            acc8(a, *(const uint4*)(hs1 + (size_t)s * 32 + part * 8));
        }
    }
#pragma unroll
    for (int j = 0; j < 8; ++j) a[j] += __shfl_xor(a[j], 4);
    if (node < N && eo == 0) {
        float4 r0, r1;
        r0.x = a[0]; r0.y = a[1]; r0.z = a[2]; r0.w = a[3];
        r1.x = a[4]; r1.y = a[5]; r1.z = a[6]; r1.w = a[7];
        *(float4*)(A2 + (size_t)node * 32 + part * 8) = r0;
        *(float4*)(A2 + (size_t)node * 32 + part * 8 + 4) = r1;
    }
}

// Conv2 phase B + head: hi-half srcs (hs1 rows [N/2,N) = 3.2 MB) + self +
// A2 partial; fused W2+b2+ReLU, Wl1+bl1+ReLU, Wl4+bl4. Same 8-lane split.
__global__ void __launch_bounds__(256)
gather_conv2_hi_head(const int2* __restrict__ rowRange, const int* __restrict__ rowMid,
                     const int* __restrict__ srcs, const __half* __restrict__ hs1,
                     const float* __restrict__ A2, const float* __restrict__ dinv,
                     const float* __restrict__ W2, const float* __restrict__ b2,
                     const float* __restrict__ Wl1, const float* __restrict__ bl1,
                     const float* __restrict__ Wl4, const float* __restrict__ bl4,
                     float* __restrict__ out, int N) {
    __shared__ float A[32][33];
    __shared__ float sW2[1024];
    __shared__ float sWl1[1024];
    __shared__ float sb2[32], sbl1[32], sWl4[32];
    __shared__ float sbl4;
    int t = threadIdx.x;
    for (int i = t; i < 1024; i += 256) { sW2[i] = W2[i]; sWl1[i] = Wl1[i]; }
    if (t < 32) { sb2[t] = b2[t]; sbl1[t] = bl1[t]; sWl4[t] = Wl4[t]; }
    if (t == 0) sbl4 = bl4[0];
    int tt = blockIdx.x * 256 + t;
    int node = tt >> 3, q = tt & 7, ln = t >> 3;
    int eo = q >> 2, part = q & 3;
    float a[8] = {0.f, 0.f, 0.f, 0.f, 0.f, 0.f, 0.f, 0.f};
    if (node < N) {
        int mid = rowMid[node], end = rowRange[node].y;
        int e = mid + eo;
        if (e < end) {
            int s = srcs[e];
            for (; e + 2 < end; e += 2) {
                int snext = srcs[e + 2];            // pipelined ahead
                acc8(a, *(const uint4*)(hs1 + (size_t)s * 32 + part * 8));
                s = snext;
            }
            acc8(a, *(const uint4*)(hs1 + (size_t)s * 32 + part * 8));
        }
        if (eo == 0)                                // self, counted once
            acc8(a, *(const uint4*)(hs1 + (size_t)node * 32 + part * 8));
    }
#pragma unroll
    for (int j = 0; j < 8; ++j) a[j] += __shfl_xor(a[j], 4);
    if (node < N && eo == 0) {
        float4 l0 = *(const float4*)(A2 + (size_t)node * 32 + part * 8);
        float4 l1 = *(const float4*)(A2 + (size_t)node * 32 + part * 8 + 4);
        a[0] += l0.x; a[1] += l0.y; a[2] += l0.z; a[3] += l0.w;
        a[4] += l1.x; a[5] += l1.y; a[6] += l1.z; a[7] += l1.w;
        float di = dinv[node];
#pragma unroll
        for (int j = 0; j < 8; ++j) a[j] *= di;
#pragma unroll
        for (int j = 0; j < 8; ++j) A[ln][part * 8 + j] = a[j];
    }
    __syncthreads();
    int k0 = q * 4;
    float h2[4];
#pragma unroll
    for (int j = 0; j < 4; ++j) h2[j] = sb2[k0 + j];
#pragma unroll
    for (int c = 0; c < 32; ++c) {
        float ac = A[ln][c];
#pragma unroll
        for (int j = 0; j < 4; ++j) h2[j] += ac * sW2[c * 32 + k0 + j];
    }
#pragma unroll
    for (int j = 0; j < 4; ++j) h2[j] = fmaxf(h2[j], 0.f);
    __syncthreads();
#pragma unroll
    for (int j = 0; j < 4; ++j) A[ln][k0 + j] = h2[j];
    __syncthreads();
    float h3[4];
#pragma unroll
    for (int j = 0; j < 4; ++j) h3[j] = sbl1[k0 + j];
#pragma unroll
    for (int c = 0; c < 32; ++c) {
        float ac = A[ln][c];
#pragma unroll
        for (int j = 0; j < 4; ++j) h3[j] += ac * sWl1[c * 32 + k0 + j];
    }
    float p = 0.f;
#pragma unroll
    for (int j = 0; j < 4; ++j) p += fmaxf(h3[j], 0.f) * sWl4[k0 + j];
    p += __shfl_xor(p, 1);
    p += __shfl_xor(p, 2);
    p += __shfl_xor(p, 4);
    if (q == 0 && node < N) out[node] = p + sbl4;
}

extern "C" void kernel_launch(void* const* d_in, const int* in_sizes, int n_in,
                              void* d_out, int out_size, void* d_ws, size_t ws_size,
                              hipStream_t stream) {
    const float* x   = (const float*)d_in[0];
    const int*   ei  = (const int*)d_in[1];
    const float* W1  = (const float*)d_in[2];
    const float* b1  = (const float*)d_in[3];
    const float* W2  = (const float*)d_in[4];
    const float* b2  = (const float*)d_in[5];
    const float* Wl1 = (const float*)d_in[6];
    const float* bl1 = (const float*)d_in[7];
    const float* Wl4 = (const float*)d_in[8];
    const float* bl4 = (const float*)d_in[9];
    float* out = (float*)d_out;

    const int N = in_sizes[0] / 16;
    const int E = in_sizes[1] / 2;
    const int* row = ei;        // edge_index[0] : source j
    const int* col = ei + E;    // edge_index[1] : target i
    const int NB = (N + BN - 1) >> BSH;
    const int halfN = N / 2;
    // fixed per-bucket capacity: mean * 1.125, rounded up to 64
    int C = (E + NB - 1) / NB;
    C = (C * 9 + 7) / 8;
    C = (C + 63) & ~63;

    // workspace layout (512B aligned)
    char* ws = (char*)d_ws;
    auto align = [](size_t v) { return (v + 511) & ~(size_t)511; };
    size_t o = 0;
    int*    gCursor  = (int*)(ws + o);    o = align(o + (size_t)NBUF * 4);
    int2*   rowRange = (int2*)(ws + o);   o = align(o + (size_t)N * 8);
    int*    rowMid   = (int*)(ws + o);    o = align(o + (size_t)N * 4);
    float*  dinv     = (float*)(ws + o);  o = align(o + (size_t)N * 4);
    int*    packed   = (int*)(ws + o);    o = align(o + (size_t)NB * C * 4);
    int*    srcs     = (int*)(ws + o);    o = align(o + (size_t)NB * C * 4);
    __half* xs       = (__half*)(ws + o); o = align(o + (size_t)N * 16 * 2);
    __half* hs1      = (__half*)(ws + o); o = align(o + (size_t)N * 32 * 2);
    float*  A2       = (float*)(ws + o);  o = align(o + (size_t)N * 32 * 4);

    const int BLK = 256;
    int gridSc = (E + EPB - 1) / EPB;
    int gridG8 = (N * 8 + BLK - 1) / BLK;

    // --- edge reorder + degrees + prescale ---
    init_cursor<<<1, BLK, 0, stream>>>(gCursor, NB, C);
    bucket_scatter<<<gridSc, 512, 0, stream>>>(row, col, gCursor, packed, E, NB, C);
    bucket_finalize<<<NB, 1024, 0, stream>>>(packed, gCursor, rowRange, rowMid, dinv,
                                             srcs, (const float4*)x, xs, N, C, halfN);

    // --- conv1 (gather xs + fused W1) ---
    gather_conv1<<<gridG8, BLK, 0, stream>>>(rowRange, srcs, xs, dinv, W1, b1, hs1, N);

    // --- conv2 two-phase (each phase's random set = one 3.2 MB half of hs1) ---
    gather_conv2_lo<<<gridG8, BLK, 0, stream>>>(rowRange, rowMid, srcs, hs1, A2, N);
    gather_conv2_hi_head<<<gridG8, BLK, 0, stream>>>(rowRange, rowMid, srcs, hs1, A2,
                                                     dinv, W2, b2, Wl1, bl1,
                                                     Wl4, bl4, out, N);
}

// Round 19
// 214.208 us; speedup vs baseline: 1.2496x; 1.0126x over previous
//
#include <hip/hip_runtime.h>
#include <hip/hip_fp16.h>
#include <math.h>

// ---------------------------------------------------------------------------
// GCN forward, fully fused, fp16 feature tables (fp32 accumulate).
//   xs  = fp16(dinv .* x)   [N,16] half (3.2 MB, L2-resident)
//   hs1 = fp16(dinv .* h1)  [N,32] half (6.4 MB)
// Edge layout: bucket b = 512 dst nodes, fixed-capacity gapped region of C
// edges at b*C. Lists sorted by (dstLocal, srcHalf): rowRange[n]=(beg,end),
// rowMid[n] = boundary between srcs < N/2 and srcs >= N/2.
// conv2 runs as two kernels so each one's random working set is one 3.2 MB
// contiguous half of hs1 (fits a 4 MiB per-XCD L2).
// Gathers: 8 lanes/node = (edge-offset x row-part), 16 B loads, grid 3125;
// 2-deep software pipeline: 2 feature loads + 2 index loads in flight/lane.
// ---------------------------------------------------------------------------

#define BN 512           // nodes per bucket
#define BSH 9            // log2(BN)
#define NBUF 256         // max buckets (N <= 131072)
#define EPB 4096         // edges per scatter block
#define EPT 8            // edges per scatter thread (EPB/512)

__global__ void init_cursor(int* __restrict__ gCursor, int NB, int C) {
    int b = blockIdx.x * blockDim.x + threadIdx.x;
    if (b < NB) gCursor[b] = b * C;
}

// Scatter edges into bucket-gapped packed array ((src<<9)|dstLocal).
// 512 threads/block; single LDS-atomic pass, rank in registers.
__global__ void __launch_bounds__(512)
bucket_scatter(const int* __restrict__ row, const int* __restrict__ col,
               int* __restrict__ gCursor, int* __restrict__ packed,
               int E, int NB, int C) {
    __shared__ int hist[NBUF];
    __shared__ int base[NBUF];
    int t = threadIdx.x;
    int blockBase = blockIdx.x * EPB;
    for (int i = t; i < NB; i += 512) hist[i] = 0;
    __syncthreads();
    int pay[EPT];
    int meta[EPT];
#pragma unroll
    for (int k = 0; k < EPT; ++k) {
        int e = blockBase + k * 512 + t;
        if (e < E) {
            int c = col[e];
            int b = c >> BSH;
            int r = atomicAdd(&hist[b], 1);        // rank within (block,bucket)
            pay[k] = (row[e] << BSH) | (c & (BN - 1));
            meta[k] = (b << 16) | r;               // r < 4096 fits 16 bits
        } else {
            meta[k] = -1;
        }
    }
    __syncthreads();
    for (int b = t; b < NB; b += 512) {            // claim global ranges
        int c = hist[b];
        base[b] = c ? atomicAdd(&gCursor[b], c) : 0;
    }
    __syncthreads();
#pragma unroll
    for (int k = 0; k < EPT; ++k) {                // write
        int m = meta[k];
        if (m >= 0) {
            int b = m >> 16;
            int pos = base[b] + (m & 0xFFFF);
            if (pos < (b + 1) * C)                 // overflow guard (~16 sigma)
                packed[pos] = pay[k];
        }
    }
}

// Per bucket (1024 threads): 1024-bin hist (dstLocal*2 + srcHalf) -> rowRange
// + rowMid + dinv, counting-sort -> srcs[] ordered (dl, srcHalf), prescale xs.
// Scan via shfl wave-scan + cross-wave scan.
__global__ void __launch_bounds__(1024)
bucket_finalize(const int* __restrict__ packed, const int* __restrict__ gCursor,
                int2* __restrict__ rowRange, int* __restrict__ rowMid,
                float* __restrict__ dinv, int* __restrict__ srcs,
                const float4* __restrict__ x4, __half* __restrict__ xs,
                int N, int C, int halfN) {
    __shared__ int cnt[BN * 2];
    __shared__ int cur[BN * 2];
    __shared__ float sdv[BN];
    __shared__ int wsum[16];
    int bkt = blockIdx.x;
    int t = threadIdx.x;
    int nodeBase = bkt << BSH;
    cnt[t] = 0;
    __syncthreads();
    int beg = bkt * C;
    int end = min(gCursor[bkt], beg + C);
    for (int e = beg + t; e < end; e += 1024) {
        int w = packed[e];
        int key = ((w & (BN - 1)) << 1) | ((w >> BSH) >= halfN ? 1 : 0);
        atomicAdd(&cnt[key], 1);
    }
    __syncthreads();
    // thread t (< BN) owns bins 2t,2t+1 = node t (local)
    int c0 = (t < BN) ? cnt[2 * t] : 0;
    int c1 = (t < BN) ? cnt[2 * t + 1] : 0;
    int s = c0 + c1;
    // inclusive scan of s: shfl within wave, then cross-wave offsets
    int lane = t & 63, wv = t >> 6;
    int v = s;
#pragma unroll
    for (int off = 1; off < 64; off <<= 1) {
        int u = __shfl_up(v, off);
        if (lane >= off) v += u;
    }
    if (lane == 63) wsum[wv] = v;
    __syncthreads();
    int addv = 0;
#pragma unroll
    for (int w = 0; w < 16; ++w) addv += (w < wv) ? wsum[w] : 0;
    v += addv;
    if (t < BN) {
        int p = beg + v - s;                       // exclusive prefix
        cur[2 * t] = p;
        cur[2 * t + 1] = p + c0;
        float d = rsqrtf((float)s + 1.0f);
        sdv[t] = d;
        int n = nodeBase + t;
        if (n < N) {
            rowRange[n] = make_int2(p, p + s);
            rowMid[n] = p + c0;
            dinv[n] = d;
        }
    }
    __syncthreads();
    for (int e = beg + t; e < end; e += 1024) {    // counting sort (2nd read: L2)
        int w = packed[e];
        int src = w >> BSH;
        int key = ((w & (BN - 1)) << 1) | (src >= halfN ? 1 : 0);
        int pos = atomicAdd(&cur[key], 1);
        srcs[pos] = src;
    }
    // prescale: xs = fp16(dinv .* x); 2 threads/node, 16B (8 halves) each
    {
        int n = t >> 1, hf = t & 1;                 // BN*2 == 1024 exactly
        int g = nodeBase + n;
        if (g < N) {
            float d = sdv[n];
            float4 va = x4[(size_t)g * 4 + hf * 2];
            float4 vb = x4[(size_t)g * 4 + hf * 2 + 1];
            __half2 h0 = __floats2half2_rn(va.x * d, va.y * d);
            __half2 h1 = __floats2half2_rn(va.z * d, va.w * d);
            __half2 h2 = __floats2half2_rn(vb.x * d, vb.y * d);
            __half2 h3 = __floats2half2_rn(vb.z * d, vb.w * d);
            uint4 u;
            u.x = *(unsigned*)&h0; u.y = *(unsigned*)&h1;
            u.z = *(unsigned*)&h2; u.w = *(unsigned*)&h3;
            *(uint4*)(xs + (size_t)g * 16 + hf * 8) = u;
        }
    }
}

__device__ __forceinline__ void acc8(float* a, uint4 u) {
    float2 f;
    f = __half22float2(*(const __half2*)&u.x); a[0] += f.x; a[1] += f.y;
    f = __half22float2(*(const __half2*)&u.y); a[2] += f.x; a[3] += f.y;
    f = __half22float2(*(const __half2*)&u.z); a[4] += f.x; a[5] += f.y;
    f = __half22float2(*(const __half2*)&u.w); a[6] += f.x; a[7] += f.y;
}

// 2-deep pipelined gather over strided edge list [first, limit) step `stride`,
// accumulating 16B rows tbl[src*rowHalves + off8*8]. Branch-free tail clamp.
__device__ __forceinline__ void gather_pipe(float* a, const int* __restrict__ srcs,
                                            const __half* __restrict__ tbl,
                                            int rowHalves, int off8,
                                            int first, int limit, int stride) {
    if (first >= limit) return;
    int cntE = (limit - first + stride - 1) / stride;
    int last = limit - 1;
    int sA = srcs[first];
    int sB = (cntE > 1) ? srcs[first + stride] : 0;
    int i = 0;
    for (; i + 2 <= cntE; i += 2) {
        int nA = srcs[min(first + stride * (i + 2), last)];
        int nB = srcs[min(first + stride * (i + 3), last)];
        uint4 fA = *(const uint4*)(tbl + (size_t)sA * rowHalves + off8 * 8);
        uint4 fB = *(const uint4*)(tbl + (size_t)sB * rowHalves + off8 * 8);
        acc8(a, fA);
        acc8(a, fB);
        sA = nA; sB = nB;
    }
    if (i < cntE)
        acc8(a, *(const uint4*)(tbl + (size_t)sA * rowHalves + off8 * 8));
}

// Layer 1: gather xs (16ch half), fused W1 GEMM + bias + ReLU; hs1=fp16(dinv.*h1).
// 8 lanes/node = (eo in [0,4)) x (hf in [0,2)); 2-deep pipelined gather.
__global__ void __launch_bounds__(256)
gather_conv1(const int2* __restrict__ rowRange, const int* __restrict__ srcs,
             const __half* __restrict__ xs, const float* __restrict__ dinv,
             const float* __restrict__ W1, const float* __restrict__ b1,
             __half* __restrict__ hs1, int N) {
    __shared__ float A[32][17];
    __shared__ float sW[512];
    __shared__ float sb[32];
    int t = threadIdx.x;
    for (int i = t; i < 512; i += 256) sW[i] = W1[i];
    if (t < 32) sb[t] = b1[t];
    int tt = blockIdx.x * 256 + t;
    int node = tt >> 3, q = tt & 7, ln = t >> 3;
    int eo = q >> 1, hf = q & 1;
    float a[8] = {0.f, 0.f, 0.f, 0.f, 0.f, 0.f, 0.f, 0.f};
    float di = 0.f;
    if (node < N) {
        int2 rr = rowRange[node];
        gather_pipe(a, srcs, xs, 16, hf, rr.x + eo, rr.y, 4);
        if (eo == 0)                                // self, counted once
            acc8(a, *(const uint4*)(xs + (size_t)node * 16 + hf * 8));
        di = dinv[node];
    }
    // reduce over eo (q bits 1..2)
#pragma unroll
    for (int j = 0; j < 8; ++j) {
        a[j] += __shfl_xor(a[j], 2);
        a[j] += __shfl_xor(a[j], 4);
        a[j] *= di;
    }
    if (eo == 0) {                                  // q = 0 (hf0), 1 (hf1)
#pragma unroll
        for (int j = 0; j < 8; ++j) A[ln][hf * 8 + j] = a[j];
    }
    __syncthreads();
    if (node < N) {
        int k0 = q * 4;
        float acc[4];
#pragma unroll
        for (int j = 0; j < 4; ++j) acc[j] = sb[k0 + j];
#pragma unroll
        for (int c = 0; c < 16; ++c) {
            float ac = A[ln][c];
#pragma unroll
            for (int j = 0; j < 4; ++j) acc[j] += ac * sW[c * 32 + k0 + j];
        }
        __half2 h0 = __floats2half2_rn(di * fmaxf(acc[0], 0.f),
                                       di * fmaxf(acc[1], 0.f));
        __half2 h1 = __floats2half2_rn(di * fmaxf(acc[2], 0.f),
                                       di * fmaxf(acc[3], 0.f));
        uint2 u;
        u.x = *(unsigned*)&h0; u.y = *(unsigned*)&h1;
        *(uint2*)(hs1 + (size_t)node * 32 + k0) = u;
    }
}

// Conv2 phase A: sum lo-half srcs (hs1 rows [0,N/2) = 3.2 MB, L2-resident)
// -> A2[N,32] fp32. 8 lanes/node = (eo in [0,2)) x (part in [0,4)).
__global__ void __launch_bounds__(256)
gather_conv2_lo(const int2* __restrict__ rowRange, const int* __restrict__ rowMid,
                const int* __restrict__ srcs, const __half* __restrict__ hs1,
                float* __restrict__ A2, int N) {
    int tt = blockIdx.x * 256 + threadIdx.x;
    int node = tt >> 3, q = tt & 7;
    int eo = q >> 2, part = q & 3;
    float a[8] = {0.f, 0.f, 0.f, 0.f, 0.f, 0.f, 0.f, 0.f};
    if (node < N) {
        int beg = rowRange[node].x, mid = rowMid[node];
        gather_pipe(a, srcs, hs1, 32, part, beg + eo, mid, 2);
    }
#pragma unroll
    for (int j = 0; j < 8; ++j) a[j] += __shfl_xor(a[j], 4);
    if (node < N && eo == 0) {
        float4 r0, r1;
        r0.x = a[0]; r0.y = a[1]; r0.z = a[2]; r0.w = a[3];
        r1.x = a[4]; r1.y = a[5]; r1.z = a[6]; r1.w = a[7];
        *(float4*)(A2 + (size_t)node * 32 + part * 8) = r0;
        *(float4*)(A2 + (size_t)node * 32 + part * 8 + 4) = r1;
    }
}

// Conv2 phase B + head: hi-half srcs (hs1 rows [N/2,N) = 3.2 MB) + self +
// A2 partial; fused W2+b2+ReLU, Wl1+bl1+ReLU, Wl4+bl4. Same 8-lane split.
__global__ void __launch_bounds__(256)
gather_conv2_hi_head(const int2* __restrict__ rowRange, const int* __restrict__ rowMid,
                     const int* __restrict__ srcs, const __half* __restrict__ hs1,
                     const float* __restrict__ A2, const float* __restrict__ dinv,
                     const float* __restrict__ W2, const float* __restrict__ b2,
                     const float* __restrict__ Wl1, const float* __restrict__ bl1,
                     const float* __restrict__ Wl4, const float* __restrict__ bl4,
                     float* __restrict__ out, int N) {
    __shared__ float A[32][33];
    __shared__ float sW2[1024];
    __shared__ float sWl1[1024];
    __shared__ float sb2[32], sbl1[32], sWl4[32];
    __shared__ float sbl4;
    int t = threadIdx.x;
    for (int i = t; i < 1024; i += 256) { sW2[i] = W2[i]; sWl1[i] = Wl1[i]; }
    if (t < 32) { sb2[t] = b2[t]; sbl1[t] = bl1[t]; sWl4[t] = Wl4[t]; }
    if (t == 0) sbl4 = bl4[0];
    int tt = blockIdx.x * 256 + t;
    int node = tt >> 3, q = tt & 7, ln = t >> 3;
    int eo = q >> 2, part = q & 3;
    float a[8] = {0.f, 0.f, 0.f, 0.f, 0.f, 0.f, 0.f, 0.f};
    if (node < N) {
        int mid = rowMid[node], end = rowRange[node].y;
        gather_pipe(a, srcs, hs1, 32, part, mid + eo, end, 2);
        if (eo == 0)                                // self, counted once
            acc8(a, *(const uint4*)(hs1 + (size_t)node * 32 + part * 8));
    }
#pragma unroll
    for (int j = 0; j < 8; ++j) a[j] += __shfl_xor(a[j], 4);
    if (node < N && eo == 0) {
        float4 l0 = *(const float4*)(A2 + (size_t)node * 32 + part * 8);
        float4 l1 = *(const float4*)(A2 + (size_t)node * 32 + part * 8 + 4);
        a[0] += l0.x; a[1] += l0.y; a[2] += l0.z; a[3] += l0.w;
        a[4] += l1.x; a[5] += l1.y; a[6] += l1.z; a[7] += l1.w;
        float di = dinv[node];
#pragma unroll
        for (int j = 0; j < 8; ++j) a[j] *= di;
#pragma unroll
        for (int j = 0; j < 8; ++j) A[ln][part * 8 + j] = a[j];
    }
    __syncthreads();
    int k0 = q * 4;
    float h2[4];
#pragma unroll
    for (int j = 0; j < 4; ++j) h2[j] = sb2[k0 + j];
#pragma unroll
    for (int c = 0; c < 32; ++c) {
        float ac = A[ln][c];
#pragma unroll
        for (int j = 0; j < 4; ++j) h2[j] += ac * sW2[c * 32 + k0 + j];
    }
#pragma unroll
    for (int j = 0; j < 4; ++j) h2[j] = fmaxf(h2[j], 0.f);
    __syncthreads();
#pragma unroll
    for (int j = 0; j < 4; ++j) A[ln][k0 + j] = h2[j];
    __syncthreads();
    float h3[4];
#pragma unroll
    for (int j = 0; j < 4; ++j) h3[j] = sbl1[k0 + j];
#pragma unroll
    for (int c = 0; c < 32; ++c) {
        float ac = A[ln][c];
#pragma unroll
        for (int j = 0; j < 4; ++j) h3[j] += ac * sWl1[c * 32 + k0 + j];
    }
    float p = 0.f;
#pragma unroll
    for (int j = 0; j < 4; ++j) p += fmaxf(h3[j], 0.f) * sWl4[k0 + j];
    p += __shfl_xor(p, 1);
    p += __shfl_xor(p, 2);
    p += __shfl_xor(p, 4);
    if (q == 0 && node < N) out[node] = p + sbl4;
}

extern "C" void kernel_launch(void* const* d_in, const int* in_sizes, int n_in,
                              void* d_out, int out_size, void* d_ws, size_t ws_size,
                              hipStream_t stream) {
    const float* x   = (const float*)d_in[0];
    const int*   ei  = (const int*)d_in[1];
    const float* W1  = (const float*)d_in[2];
    const float* b1  = (const float*)d_in[3];
    const float* W2  = (const float*)d_in[4];
    const float* b2  = (const float*)d_in[5];
    const float* Wl1 = (const float*)d_in[6];
    const float* bl1 = (const float*)d_in[7];
    const float* Wl4 = (const float*)d_in[8];
    const float* bl4 = (const float*)d_in[9];
    float* out = (float*)d_out;

    const int N = in_sizes[0] / 16;
    const int E = in_sizes[1] / 2;
    const int* row = ei;        // edge_index[0] : source j
    const int* col = ei + E;    // edge_index[1] : target i
    const int NB = (N + BN - 1) >> BSH;
    const int halfN = N / 2;
    // fixed per-bucket capacity: mean * 1.125, rounded up to 64
    int C = (E + NB - 1) / NB;
    C = (C * 9 + 7) / 8;
    C = (C + 63) & ~63;

    // workspace layout (512B aligned)
    char* ws = (char*)d_ws;
    auto align = [](size_t v) { return (v + 511) & ~(size_t)511; };
    size_t o = 0;
    int*    gCursor  = (int*)(ws + o);    o = align(o + (size_t)NBUF * 4);
    int2*   rowRange = (int2*)(ws + o);   o = align(o + (size_t)N * 8);
    int*    rowMid   = (int*)(ws + o);    o = align(o + (size_t)N * 4);
    float*  dinv     = (float*)(ws + o);  o = align(o + (size_t)N * 4);
    int*    packed   = (int*)(ws + o);    o = align(o + (size_t)NB * C * 4);
    int*    srcs     = (int*)(ws + o);    o = align(o + (size_t)NB * C * 4);
    __half* xs       = (__half*)(ws + o); o = align(o + (size_t)N * 16 * 2);
    __half* hs1      = (__half*)(ws + o); o = align(o + (size_t)N * 32 * 2);
    float*  A2       = (float*)(ws + o);  o = align(o + (size_t)N * 32 * 4);

    const int BLK = 256;
    int gridSc = (E + EPB - 1) / EPB;
    int gridG8 = (N * 8 + BLK - 1) / BLK;

    // --- edge reorder + degrees + prescale ---
    init_cursor<<<1, BLK, 0, stream>>>(gCursor, NB, C);
    bucket_scatter<<<gridSc, 512, 0, stream>>>(row, col, gCursor, packed, E, NB, C);
    bucket_finalize<<<NB, 1024, 0, stream>>>(packed, gCursor, rowRange, rowMid, dinv,
                                             srcs, (const float4*)x, xs, N, C, halfN);

    // --- conv1 (gather xs + fused W1) ---
    gather_conv1<<<gridG8, BLK, 0, stream>>>(rowRange, srcs, xs, dinv, W1, b1, hs1, N);

    // --- conv2 two-phase (each phase's random set = one 3.2 MB half of hs1) ---
    gather_conv2_lo<<<gridG8, BLK, 0, stream>>>(rowRange, rowMid, srcs, hs1, A2, N);
    gather_conv2_hi_head<<<gridG8, BLK, 0, stream>>>(rowRange, rowMid, srcs, hs1, A2,
                                                     dinv, W2, b2, Wl1, bl1,
                                                     Wl4, bl4, out, N);
}